// Round 4
// baseline (129.762 us; speedup 1.0000x reference)
//
#include <hip/hip_runtime.h>

typedef short bf16x8 __attribute__((ext_vector_type(8)));
typedef float f32x4 __attribute__((ext_vector_type(4)));
typedef float f32x16 __attribute__((ext_vector_type(16)));
typedef unsigned int u32x4 __attribute__((ext_vector_type(4)));
typedef unsigned short u16;
typedef unsigned int u32;

#define DEVI static __device__ __forceinline__

// Problem constants
#define NB 16
#define NS 2048
#define NW 768
#define NH 64

DEVI u16 f2bf(float x) {
  u32 u = __builtin_bit_cast(u32, x);
  u += 0x7fffu + ((u >> 16) & 1u);
  return (u16)(u >> 16);
}

DEVI u32 cvtpk(float lo, float hi) {
  u32 r;
  asm("v_cvt_pk_bf16_f32 %0, %1, %2" : "=v"(r) : "v"(lo), "v"(hi));
  return r;
}

DEVI f32x4 mfma16(bf16x8 a, bf16x8 b, f32x4 c) {
  return __builtin_amdgcn_mfma_f32_16x16x32_bf16(a, b, c, 0, 0, 0);
}
DEVI f32x16 mfma32(bf16x8 a, bf16x8 b, f32x16 c) {
  return __builtin_amdgcn_mfma_f32_32x32x16_bf16(a, b, c, 0, 0, 0);
}

// XOR swizzle for width-64-bf16 LDS tiles: breaks the 128B-row-stride bank conflict.
DEVI int swz(int row, int col) { return ((row * 64 + col) * 2) ^ ((row & 7) << 4); }

// ---------------------------------------------------------------------------
// Kernel 0: rearrange Wq/Wk/Wv (fp32 [768][64]) into bf16 MFMA-B-fragment order.
// ---------------------------------------------------------------------------
__global__ __launch_bounds__(256) void prep_weights(
    const float* __restrict__ Wq, const float* __restrict__ Wk,
    const float* __restrict__ Wv, u16* __restrict__ wsW) {
  int tid = blockIdx.x * 256 + threadIdx.x;
  int tile = tid >> 6, lane = tid & 63;
  int p = tile / 96, rem = tile % 96;
  int nct = rem / 24, kch = rem % 24;
  const float* Wsrc = (p == 0) ? Wq : ((p == 1) ? Wk : Wv);
  int k0 = kch * 32 + (lane >> 4) * 8;
  int n = nct * 16 + (lane & 15);
  u16 h[8];
#pragma unroll
  for (int i = 0; i < 8; i++) h[i] = f2bf(Wsrc[(k0 + i) * NH + n]);
  uint4 v;
  v.x = (u32)h[0] | ((u32)h[1] << 16);
  v.y = (u32)h[2] | ((u32)h[3] << 16);
  v.z = (u32)h[4] | ((u32)h[5] << 16);
  v.w = (u32)h[6] | ((u32)h[7] << 16);
  ((uint4*)wsW)[tile * 64 + lane] = v;
}

// ---------------------------------------------------------------------------
// Kernel 0b: mask -> additive float bias (0 valid, -1e5 masked).
// ---------------------------------------------------------------------------
__global__ __launch_bounds__(256) void prep_bias(const int* __restrict__ mask,
                                                 float* __restrict__ biasF) {
  int i = blockIdx.x * 256 + threadIdx.x;
  biasF[i] = mask[i] ? 0.0f : -1.0e5f;
}

// ---------------------------------------------------------------------------
// Kernel 1: fused QKV projection (unchanged from round 3).
// ---------------------------------------------------------------------------
__global__ __launch_bounds__(512) void qkv_proj(
    const float* __restrict__ inp, const u16* __restrict__ wsW,
    const float* __restrict__ bq, const float* __restrict__ bk,
    const float* __restrict__ bv, u16* __restrict__ Q, u16* __restrict__ K,
    u16* __restrict__ Vt) {
  __shared__ __align__(16) u16 A_lds[128 * 64];  // 16 KB, swizzled
  __shared__ __align__(16) u16 W_lds[24 * 512];  // 24 KB, frag-order tiles
  int tid = threadIdx.x;
  int w = tid >> 6, lane = tid & 63, g = lane >> 4, l15 = lane & 15;
  int wr = w & 3, wc = w >> 2;
  int row0 = blockIdx.x * 128;

  f32x4 acc[2][6];
#pragma unroll
  for (int rt = 0; rt < 2; rt++)
#pragma unroll
    for (int ct = 0; ct < 6; ct++) acc[rt][ct] = (f32x4)0.0f;

  float4 a_reg[4];
  uint4 w_reg[3];
#pragma unroll
  for (int p = 0; p < 4; p++) {
    int id = tid + p * 512;
    int r = id >> 4, c4 = (id & 15) * 4;
    a_reg[p] = *(const float4*)(inp + (size_t)(row0 + r) * NW + c4);
  }
#pragma unroll
  for (int p = 0; p < 3; p++) {
    int id = tid + p * 512;
    int t = id >> 6, ls = id & 63;
    w_reg[p] = ((const uint4*)wsW)[((t >> 1) * 24 + (t & 1)) * 64 + ls];
  }

  for (int chunk = 0; chunk < 12; chunk++) {
    __syncthreads();
#pragma unroll
    for (int p = 0; p < 4; p++) {
      int id = tid + p * 512;
      int r = id >> 4, c4 = (id & 15) * 4;
      float4 v = a_reg[p];
      ushort4 h4;
      h4.x = f2bf(v.x); h4.y = f2bf(v.y); h4.z = f2bf(v.z); h4.w = f2bf(v.w);
      *(ushort4*)((char*)A_lds + swz(r, c4)) = h4;
    }
#pragma unroll
    for (int p = 0; p < 3; p++) {
      int id = tid + p * 512;
      int t = id >> 6, ls = id & 63;
      ((uint4*)W_lds)[t * 64 + ls] = w_reg[p];
    }
    if (chunk < 11) {
      int k0 = (chunk + 1) * 64;
#pragma unroll
      for (int p = 0; p < 4; p++) {
        int id = tid + p * 512;
        int r = id >> 4, c4 = (id & 15) * 4;
        a_reg[p] = *(const float4*)(inp + (size_t)(row0 + r) * NW + k0 + c4);
      }
#pragma unroll
      for (int p = 0; p < 3; p++) {
        int id = tid + p * 512;
        int t = id >> 6, ls = id & 63;
        w_reg[p] = ((const uint4*)
                        wsW)[((t >> 1) * 24 + (chunk + 1) * 2 + (t & 1)) * 64 + ls];
      }
    }
    __syncthreads();
    bf16x8 af[2][2];
#pragma unroll
    for (int rt = 0; rt < 2; rt++)
#pragma unroll
      for (int kk = 0; kk < 2; kk++)
        af[rt][kk] = *(const bf16x8*)((const char*)A_lds +
                                      swz(wr * 32 + rt * 16 + l15, kk * 32 + g * 8));
#pragma unroll
    for (int ct = 0; ct < 6; ct++)
#pragma unroll
      for (int kk = 0; kk < 2; kk++) {
        bf16x8 bfr = *(const bf16x8*)(W_lds +
                                      (((wc * 6 + ct) * 2 + kk) * 512 + lane * 8));
        acc[0][ct] = mfma16(af[0][kk], bfr, acc[0][ct]);
        acc[1][ct] = mfma16(af[1][kk], bfr, acc[1][ct]);
      }
  }

  int b = row0 >> 11, s0b = row0 & 2047;
#pragma unroll
  for (int ct = 0; ct < 6; ct++) {
    int gct = wc * 6 + ct;
    int p3 = gct >> 2, n = (gct & 3) * 16 + l15;
    const float* bias = (p3 == 0) ? bq : ((p3 == 1) ? bk : bv);
    float bb = bias[n];
#pragma unroll
    for (int rt = 0; rt < 2; rt++) {
      int srow = s0b + wr * 32 + rt * 16 + g * 4;
      if (p3 == 0) {
        u16* dst = Q + ((size_t)(b * NS + srow) * NH + n);
#pragma unroll
        for (int reg = 0; reg < 4; reg++)
          dst[(size_t)reg * NH] = f2bf(acc[rt][ct][reg] + bb);
      } else if (p3 == 1) {
        u16* dst = K + ((size_t)(b * NS + srow) * NH + n);
#pragma unroll
        for (int reg = 0; reg < 4; reg++)
          dst[(size_t)reg * NH] = f2bf(acc[rt][ct][reg] + bb);
      } else {
        ushort4 h4;
        h4.x = f2bf(acc[rt][ct][0] + bb);
        h4.y = f2bf(acc[rt][ct][1] + bb);
        h4.z = f2bf(acc[rt][ct][2] + bb);
        h4.w = f2bf(acc[rt][ct][3] + bb);
        *(ushort4*)(Vt + (size_t)b * NH * NS + (size_t)n * NS + srow) = h4;
      }
    }
  }
}

// ---------------------------------------------------------------------------
// Kernel 2: flash attention, 32x32 MFMA, in-register softmax and P.
// Block: 32 q-rows x batch; 4 waves each own 512 keys (16 tiles of 32).
// Swapped QK^T (mfma(K,Q)) -> lane holds q=lane&31; row reduce = 1 shfl_xor.
// Mask as additive bias; defer-max (THR=8, exp2 domain); P packed via
// v_cvt_pk_bf16_f32 + shfl_xor(32) into PV A-frags. No P LDS, no bpermute.
// ---------------------------------------------------------------------------
__global__ __launch_bounds__(256) void attn(
    const u16* __restrict__ Q, const u16* __restrict__ K,
    const u16* __restrict__ Vt, const float* __restrict__ biasF,
    float* __restrict__ out) {
  // corrL (4 waves x 32 f32, wave-private) during main loop; after the final
  // barrier aliased as accL[4][32][65] f32 + mlL[4][32][2] f32.
  __shared__ __align__(16) char smem[34304];
  int tid = threadIdx.x;
  int w = tid >> 6, lane = tid & 63;
  int l31 = lane & 31, hi = lane >> 5;
  int bid = blockIdx.x;
  int b = (bid & 7) * 2 + ((bid >> 3) & 1);  // 2 batches per XCD (L2 locality)
  int q0 = (bid >> 4) * 32;
  const u16* Qb = Q + (size_t)b * NS * NH;
  const u16* Kb = K + (size_t)b * NS * NH;
  const u16* Vb = Vt + (size_t)b * NH * NS;
  const float* bb = biasF + (size_t)b * NS;
  float* corrL = (float*)smem + w * 32;

  const float SC = 0.18033688011112043f;  // log2(e)/sqrt(64)

  // Q fragments (B-operand): col=q0+l31, k=kk*16+hi*8+j
  bf16x8 qf[4];
#pragma unroll
  for (int kk = 0; kk < 4; kk++)
    qf[kk] = *(const bf16x8*)(Qb + (size_t)(q0 + l31) * NH + kk * 16 + hi * 8);

  f32x16 acc[2];
  acc[0] = (f32x16)0.0f;
  acc[1] = (f32x16)0.0f;
  float m_run = -1.0e4f, l_run = 0.0f;

#pragma unroll 2
  for (int t = 0; t < 16; t++) {
    int kv0 = w * 512 + t * 32;
    // K A-frags: row=kv0+l31, k=kk*16+hi*8+j
    bf16x8 kf[4];
#pragma unroll
    for (int kk = 0; kk < 4; kk++)
      kf[kk] = *(const bf16x8*)(Kb + (size_t)(kv0 + l31) * NH + kk * 16 + hi * 8);
    // bias for this lane's 16 key slots: key(r) = (r&3) + 8*(r>>2) + 4*hi
    float4 b4[4];
#pragma unroll
    for (int m = 0; m < 4; m++)
      b4[m] = *(const float4*)(bb + kv0 + m * 8 + hi * 4);
    // V B-frags: col(h)=ht*32+l31, k=ks*16+hi*8+j ; Vt is [h][s]
    bf16x8 vf[2][2];
#pragma unroll
    for (int ht = 0; ht < 2; ht++)
#pragma unroll
      for (int ks = 0; ks < 2; ks++)
        vf[ht][ks] = *(const bf16x8*)(Vb + (size_t)(ht * 32 + l31) * NS + kv0 +
                                      ks * 16 + hi * 8);

    // S^T[key][q] : lane holds q=l31, keys (r&3)+8*(r>>2)+4*hi
    f32x16 sT = (f32x16)0.0f;
#pragma unroll
    for (int kk = 0; kk < 4; kk++) sT = mfma32(kf[kk], qf[kk], sT);

    // scale + bias, row max (2 lanes per row)
    float tm = -1.0e30f;
#pragma unroll
    for (int r = 0; r < 16; r++) {
      sT[r] = fmaf(sT[r], SC, b4[r >> 2][r & 3]);
      tm = fmaxf(tm, sT[r]);
    }
    tm = fmaxf(tm, __shfl_xor(tm, 32));

    // defer-max: only rescale when some row's max grew past threshold
    if (!__all(tm <= m_run + 8.0f)) {
      float mn = fmaxf(m_run, tm);
      float corr = exp2f(m_run - mn);
      m_run = mn;
      l_run *= corr;
      if (hi == 0) corrL[l31] = corr;  // wave-private; lgkmcnt orders
      float4 c4[4];
#pragma unroll
      for (int m = 0; m < 4; m++)
        c4[m] = *(const float4*)(corrL + m * 8 + hi * 4);
#pragma unroll
      for (int r = 0; r < 16; r++) {
        float cq = c4[r >> 2][r & 3];  // corr for q=(r&3)+8*(r>>2)+4*hi
        acc[0][r] *= cq;
        acc[1][r] *= cq;
      }
    }

    // P = exp2(S - m), row sum
    float p[16];
    float rs = 0.0f;
#pragma unroll
    for (int r = 0; r < 16; r++) {
      p[r] = exp2f(sT[r] - m_run);
      rs += p[r];
    }
    rs += __shfl_xor(rs, 32);
    l_run += rs;

    // pack P -> bf16 pairs; redistribute across hi with shfl_xor(32)
    u32 c[8];
#pragma unroll
    for (int i = 0; i < 8; i++) c[i] = cvtpk(p[2 * i], p[2 * i + 1]);
    u32 x[8];
#pragma unroll
    for (int i = 0; i < 8; i++)
      x[i] = (u32)__shfl_xor((int)c[i], 32);
    // A-frag rows=q=l31, k=ks*16+hi*8+j
    u32x4 w0, w1;
    w0.x = hi ? x[2] : c[0];
    w0.y = hi ? x[3] : c[1];
    w0.z = hi ? c[2] : x[0];
    w0.w = hi ? c[3] : x[1];
    w1.x = hi ? x[6] : c[4];
    w1.y = hi ? x[7] : c[5];
    w1.z = hi ? c[6] : x[4];
    w1.w = hi ? c[7] : x[5];
    bf16x8 pa0 = __builtin_bit_cast(bf16x8, w0);
    bf16x8 pa1 = __builtin_bit_cast(bf16x8, w1);

    // O += P V
    acc[0] = mfma32(pa0, vf[0][0], acc[0]);
    acc[1] = mfma32(pa0, vf[1][0], acc[1]);
    acc[0] = mfma32(pa1, vf[0][1], acc[0]);
    acc[1] = mfma32(pa1, vf[1][1], acc[1]);
  }

  // Merge the 4 KV-chunk partials via LDS
  __syncthreads();  // corrL dead; alias smem as accL/mlL
  float* accL = (float*)smem;            // [z][q][65] padded
  float* mlL = (float*)(smem + 33280);   // [z][q][2]
#pragma unroll
  for (int ht = 0; ht < 2; ht++)
#pragma unroll
    for (int r = 0; r < 16; r++) {
      int q = (r & 3) + 8 * (r >> 2) + 4 * hi;
      accL[(w * 32 + q) * 65 + ht * 32 + l31] = acc[ht][r];
    }
  if (hi == 0) {
    mlL[(w * 32 + l31) * 2 + 0] = m_run;
    mlL[(w * 32 + l31) * 2 + 1] = l_run;
  }
  __syncthreads();

#pragma unroll
  for (int i = 0; i < 8; i++) {
    int idx = tid + i * 256;  // 0..2047
    int row = idx >> 6, h = idx & 63;
    float m[4], l[4];
#pragma unroll
    for (int z = 0; z < 4; z++) {
      m[z] = mlL[(z * 32 + row) * 2 + 0];
      l[z] = mlL[(z * 32 + row) * 2 + 1];
    }
    float M = fmaxf(fmaxf(m[0], m[1]), fmaxf(m[2], m[3]));
    float den = 0.0f, o = 0.0f;
#pragma unroll
    for (int z = 0; z < 4; z++) {
      float e = exp2f(m[z] - M);
      den += e * l[z];
      o += e * accL[(z * 32 + row) * 65 + h];
    }
    out[((size_t)b * NS + q0 + row) * NH + h] = o / den;
  }
}

extern "C" void kernel_launch(void* const* d_in, const int* in_sizes, int n_in,
                              void* d_out, int out_size, void* d_ws,
                              size_t ws_size, hipStream_t stream) {
  const float* inp = (const float*)d_in[0];
  const int* mask = (const int*)d_in[1];
  const float* Wq = (const float*)d_in[2];
  const float* bq = (const float*)d_in[3];
  const float* Wk = (const float*)d_in[4];
  const float* bk = (const float*)d_in[5];
  const float* Wv = (const float*)d_in[6];
  const float* bv = (const float*)d_in[7];
  float* out = (float*)d_out;

  char* ws = (char*)d_ws;
  u16* wsW = (u16*)ws;                              // 288 KB
  u16* wsQ = (u16*)(ws + (1u << 20));               // 4 MB
  u16* wsK = (u16*)(ws + (1u << 20) + (4u << 20));  // 4 MB
  u16* wsVt = (u16*)(ws + (1u << 20) + (8u << 20)); // 4 MB
  float* wsBias = (float*)(ws + (13u << 20));       // 128 KB

  prep_weights<<<dim3(72), dim3(256), 0, stream>>>(Wq, Wk, Wv, wsW);
  prep_bias<<<dim3(NB * NS / 256), dim3(256), 0, stream>>>(mask, wsBias);
  qkv_proj<<<dim3((NB * NS) / 128), dim3(512), 0, stream>>>(inp, wsW, bq, bk,
                                                            bv, wsQ, wsK, wsVt);
  attn<<<dim3(NB * NS / 32), dim3(256), 0, stream>>>(wsQ, wsK, wsVt, wsBias,
                                                     out);
}

// Round 5
// 75.291 us; speedup vs baseline: 1.7235x; 1.7235x over previous
//
#include <hip/hip_runtime.h>

typedef short bf16x8 __attribute__((ext_vector_type(8)));
typedef float f32x4 __attribute__((ext_vector_type(4)));
typedef float f32x16 __attribute__((ext_vector_type(16)));
typedef unsigned int u32x4 __attribute__((ext_vector_type(4)));
typedef unsigned short u16;
typedef unsigned int u32;

#define DEVI static __device__ __forceinline__

// Problem constants
#define NB 16
#define NS 2048
#define NW 768
#define NH 64

DEVI u16 f2bf(float x) {
  u32 u = __builtin_bit_cast(u32, x);
  u += 0x7fffu + ((u >> 16) & 1u);
  return (u16)(u >> 16);
}

DEVI u32 cvtpk(float lo, float hi) {
  u32 r;
  asm("v_cvt_pk_bf16_f32 %0, %1, %2" : "=v"(r) : "v"(lo), "v"(hi));
  return r;
}

DEVI f32x4 mfma16(bf16x8 a, bf16x8 b, f32x4 c) {
  return __builtin_amdgcn_mfma_f32_16x16x32_bf16(a, b, c, 0, 0, 0);
}
DEVI f32x16 mfma32(bf16x8 a, bf16x8 b, f32x16 c) {
  return __builtin_amdgcn_mfma_f32_32x32x16_bf16(a, b, c, 0, 0, 0);
}

// XOR swizzle for width-64-bf16 LDS tiles.
DEVI int swz(int row, int col) { return ((row * 64 + col) * 2) ^ ((row & 7) << 4); }

// ---------------------------------------------------------------------------
// Fragment-linear layouts (so attention loads are base + lane*16B, coalesced):
//   Q_frag/K_frag: u16[(b*64+T)][kk=0..3][lane=hi*32+l31][j=0..7]
//     holds value (s, n) with T=s>>5, l31=s&31, kk=n>>4, hi=(n>>3)&1, j=n&7.
//   V_frag: u16[(b*64+T)][ks=0..1][ht=0..1][lane=hi*32+(h&31)][j]
//     holds value (s, h) with ks=bit4(s&31), hi=bit3(s&31), j=s&7, ht=h>>5.
// ---------------------------------------------------------------------------

// ---------------------------------------------------------------------------
// Kernel 0: rearrange Wq/Wk/Wv (fp32 [768][64]) into bf16 MFMA-B-fragment order.
// ---------------------------------------------------------------------------
__global__ __launch_bounds__(256) void prep_weights(
    const float* __restrict__ Wq, const float* __restrict__ Wk,
    const float* __restrict__ Wv, u16* __restrict__ wsW) {
  int tid = blockIdx.x * 256 + threadIdx.x;
  int tile = tid >> 6, lane = tid & 63;
  int p = tile / 96, rem = tile % 96;
  int nct = rem / 24, kch = rem % 24;
  const float* Wsrc = (p == 0) ? Wq : ((p == 1) ? Wk : Wv);
  int k0 = kch * 32 + (lane >> 4) * 8;
  int n = nct * 16 + (lane & 15);
  u16 h[8];
#pragma unroll
  for (int i = 0; i < 8; i++) h[i] = f2bf(Wsrc[(k0 + i) * NH + n]);
  uint4 v;
  v.x = (u32)h[0] | ((u32)h[1] << 16);
  v.y = (u32)h[2] | ((u32)h[3] << 16);
  v.z = (u32)h[4] | ((u32)h[5] << 16);
  v.w = (u32)h[6] | ((u32)h[7] << 16);
  ((uint4*)wsW)[tile * 64 + lane] = v;
}

// ---------------------------------------------------------------------------
// Kernel 0b: mask -> additive float bias (0 valid, -1e5 masked).
// ---------------------------------------------------------------------------
__global__ __launch_bounds__(256) void prep_bias(const int* __restrict__ mask,
                                                 float* __restrict__ biasF) {
  int i = blockIdx.x * 256 + threadIdx.x;
  biasF[i] = mask[i] ? 0.0f : -1.0e5f;
}

// ---------------------------------------------------------------------------
// Kernel 1: fused QKV projection. BM=32 rows/block, grid 1024 (4 blocks/CU),
// 4 waves each own 48 output cols. A register-prefetched -> LDS (bf16,
// swizzled); W fragments register-resident (prefetched, no W_lds).
// Outputs written in fragment-linear order (see above).
// ---------------------------------------------------------------------------
__global__ __launch_bounds__(256) void qkv_proj(
    const float* __restrict__ inp, const u16* __restrict__ wsW,
    const float* __restrict__ bq, const float* __restrict__ bk,
    const float* __restrict__ bv, u16* __restrict__ Qf, u16* __restrict__ Kf,
    u16* __restrict__ Vf) {
  __shared__ __align__(16) u16 A_lds[32 * 64];  // 4 KB, swizzled
  int tid = threadIdx.x;
  int w = tid >> 6, lane = tid & 63, g = lane >> 4, l15 = lane & 15;
  int row0 = blockIdx.x * 32;

  f32x4 acc[2][3];
#pragma unroll
  for (int rt = 0; rt < 2; rt++)
#pragma unroll
    for (int ct = 0; ct < 3; ct++) acc[rt][ct] = (f32x4)0.0f;

  int sr = tid >> 4, sc4 = (tid & 15) * 4;       // stage coords (pass 0)
  int sr1 = (tid + 256) >> 4;                    // stage coords (pass 1)

  float4 a_reg[2];
  bf16x8 w_reg[3][2];
  // Preload chunk 0
  a_reg[0] = *(const float4*)(inp + (size_t)(row0 + sr) * NW + sc4);
  a_reg[1] = *(const float4*)(inp + (size_t)(row0 + sr1) * NW + sc4);
#pragma unroll
  for (int ct = 0; ct < 3; ct++)
#pragma unroll
    for (int kk = 0; kk < 2; kk++)
      w_reg[ct][kk] =
          *(const bf16x8*)(wsW + (size_t)((w * 3 + ct) * 24 + kk) * 512 + lane * 8);

  for (int chunk = 0; chunk < 12; chunk++) {
    __syncthreads();  // previous compute done reading A_lds
    {
      float4 v = a_reg[0];
      ushort4 h4;
      h4.x = f2bf(v.x); h4.y = f2bf(v.y); h4.z = f2bf(v.z); h4.w = f2bf(v.w);
      *(ushort4*)((char*)A_lds + swz(sr, sc4)) = h4;
      v = a_reg[1];
      h4.x = f2bf(v.x); h4.y = f2bf(v.y); h4.z = f2bf(v.z); h4.w = f2bf(v.w);
      *(ushort4*)((char*)A_lds + swz(sr1, sc4)) = h4;
    }
    // Prefetch next chunk (clamped; last-iter redundant loads are harmless)
    int cn = (chunk < 11) ? chunk + 1 : 11;
    float4 a_nxt[2];
    bf16x8 w_nxt[3][2];
    a_nxt[0] = *(const float4*)(inp + (size_t)(row0 + sr) * NW + cn * 64 + sc4);
    a_nxt[1] = *(const float4*)(inp + (size_t)(row0 + sr1) * NW + cn * 64 + sc4);
#pragma unroll
    for (int ct = 0; ct < 3; ct++)
#pragma unroll
      for (int kk = 0; kk < 2; kk++)
        w_nxt[ct][kk] = *(const bf16x8*)(
            wsW + (size_t)((w * 3 + ct) * 24 + cn * 2 + kk) * 512 + lane * 8);
    __syncthreads();
    // Compute: 32 rows x this wave's 48 cols
    bf16x8 af[2][2];
#pragma unroll
    for (int rt = 0; rt < 2; rt++)
#pragma unroll
      for (int kk = 0; kk < 2; kk++)
        af[rt][kk] = *(const bf16x8*)((const char*)A_lds +
                                      swz(rt * 16 + l15, kk * 32 + g * 8));
#pragma unroll
    for (int ct = 0; ct < 3; ct++)
#pragma unroll
      for (int kk = 0; kk < 2; kk++) {
        acc[0][ct] = mfma16(af[0][kk], w_reg[ct][kk], acc[0][ct]);
        acc[1][ct] = mfma16(af[1][kk], w_reg[ct][kk], acc[1][ct]);
      }
    // Rotate prefetch registers
    a_reg[0] = a_nxt[0];
    a_reg[1] = a_nxt[1];
#pragma unroll
    for (int ct = 0; ct < 3; ct++)
#pragma unroll
      for (int kk = 0; kk < 2; kk++) w_reg[ct][kk] = w_nxt[ct][kk];
  }

  // Epilogue: bias add, store in fragment-linear order.
  int b = row0 >> 11;
  size_t bT = (size_t)b * 64 + ((row0 & 2047) >> 5);
#pragma unroll
  for (int ct = 0; ct < 3; ct++) {
    int gct = w * 3 + ct;
    int p3 = gct >> 2;
    int n = (gct & 3) * 16 + l15;
    const float* bias = (p3 == 0) ? bq : ((p3 == 1) ? bk : bv);
    float bbv = bias[n];
    if (p3 < 2) {
      u16* base = (p3 == 0) ? Qf : Kf;
      int kk = gct & 3;
      int hin = (l15 >> 3) & 1, j = l15 & 7;
#pragma unroll
      for (int rt = 0; rt < 2; rt++)
#pragma unroll
        for (int reg = 0; reg < 4; reg++)
          base[((bT * 4 + kk) * 64 + hin * 32 + rt * 16 + g * 4 + reg) * 8 + j] =
              f2bf(acc[rt][ct][reg] + bbv);
    } else {
      int ht = n >> 5, lanev = ((g >> 1) & 1) * 32 + (n & 31), jb = (g & 1) * 4;
#pragma unroll
      for (int rt = 0; rt < 2; rt++) {
        uint2 pp;
        pp.x = (u32)f2bf(acc[rt][ct][0] + bbv) |
               ((u32)f2bf(acc[rt][ct][1] + bbv) << 16);
        pp.y = (u32)f2bf(acc[rt][ct][2] + bbv) |
               ((u32)f2bf(acc[rt][ct][3] + bbv) << 16);
        *(uint2*)(Vf + (((bT * 2 + rt) * 2 + ht) * 64 + lanev) * 8 + jb) = pp;
      }
    }
  }
}

// ---------------------------------------------------------------------------
// Kernel 2: flash attention, 32x32 MFMA, fragment-linear operands.
// Block: 32 q-rows x batch; 4 waves each own 512 keys (16 tiles of 32).
// All operand loads are base + lane*16B (coalesced, L2-hit). Next K-tile
// register-prefetched; V/bias issued early, consumed late (self-hiding).
// Swapped QK^T; mask as additive bias; defer-max; in-register P pack.
// ---------------------------------------------------------------------------
__global__ __launch_bounds__(256) void attn(
    const u16* __restrict__ Qf, const u16* __restrict__ Kf,
    const u16* __restrict__ Vf, const float* __restrict__ biasF,
    float* __restrict__ out) {
  // corrL (4 x 32 f32, wave-private) during main loop; then aliased as
  // accL[4][32][65] f32 + mlL[4][32][2] f32 for the merge.
  __shared__ __align__(16) char smem[34304];
  int tid = threadIdx.x;
  int w = tid >> 6, lane = tid & 63;
  int l31 = lane & 31, hi = lane >> 5;
  int bid = blockIdx.x;
  int b = (bid & 7) * 2 + ((bid >> 3) & 1);  // 2 batches per XCD (L2 locality)
  int q0t = bid >> 4;                        // q-tile (32 rows) 0..63
  const float* bb = biasF + (size_t)b * NS;
  float* corrL = (float*)smem + w * 32;

  const float SC = 0.18033688011112043f;  // log2(e)/sqrt(64)

  // Q fragments (coalesced frag-linear load)
  size_t bQT = (size_t)b * 64 + q0t;
  bf16x8 qf[4];
#pragma unroll
  for (int kk = 0; kk < 4; kk++)
    qf[kk] = *(const bf16x8*)(Qf + (bQT * 4 + kk) * 512 + lane * 8);

  f32x16 acc[2];
  acc[0] = (f32x16)0.0f;
  acc[1] = (f32x16)0.0f;
  float m_run = -1.0e4f, l_run = 0.0f;

  // First K tile of this wave's chunk
  size_t tbase = (size_t)b * 64 + w * 16;
  bf16x8 kf[4];
#pragma unroll
  for (int kk = 0; kk < 4; kk++)
    kf[kk] = *(const bf16x8*)(Kf + (tbase * 4 + kk) * 512 + lane * 8);

  for (int t = 0; t < 16; t++) {
    int kv0 = w * 512 + t * 32;
    size_t bKT = tbase + t;
    size_t bKN = tbase + ((t < 15) ? t + 1 : t);
    // Prefetch next K tile (register double-buffer)
    bf16x8 kn[4];
#pragma unroll
    for (int kk = 0; kk < 4; kk++)
      kn[kk] = *(const bf16x8*)(Kf + (bKN * 4 + kk) * 512 + lane * 8);
    // V fragments + bias: issued now, consumed after softmax (self-hiding)
    bf16x8 vf[2][2];
#pragma unroll
    for (int ht = 0; ht < 2; ht++)
#pragma unroll
      for (int ks = 0; ks < 2; ks++)
        vf[ht][ks] = *(const bf16x8*)(Vf + ((bKT * 2 + ks) * 2 + ht) * 512 +
                                      lane * 8);
    float4 b4[4];
#pragma unroll
    for (int m = 0; m < 4; m++)
      b4[m] = *(const float4*)(bb + kv0 + m * 8 + hi * 4);

    // S^T[key][q] : lane holds q=l31, keys (r&3)+8*(r>>2)+4*hi
    f32x16 sT = (f32x16)0.0f;
#pragma unroll
    for (int kk = 0; kk < 4; kk++) sT = mfma32(kf[kk], qf[kk], sT);

    // scale + mask-bias, row max (2 lanes per row)
    float tm = -1.0e30f;
#pragma unroll
    for (int r = 0; r < 16; r++) {
      sT[r] = fmaf(sT[r], SC, b4[r >> 2][r & 3]);
      tm = fmaxf(tm, sT[r]);
    }
    tm = fmaxf(tm, __shfl_xor(tm, 32));

    // defer-max: rescale only when some row's max grew past threshold
    if (!__all(tm <= m_run + 8.0f)) {
      float mn = fmaxf(m_run, tm);
      float corr = exp2f(m_run - mn);
      m_run = mn;
      l_run *= corr;
      if (hi == 0) corrL[l31] = corr;  // wave-private; lgkmcnt orders
      float4 c4[4];
#pragma unroll
      for (int m = 0; m < 4; m++)
        c4[m] = *(const float4*)(corrL + m * 8 + hi * 4);
#pragma unroll
      for (int r = 0; r < 16; r++) {
        float cq = c4[r >> 2][r & 3];
        acc[0][r] *= cq;
        acc[1][r] *= cq;
      }
    }

    // P = exp2(S - m), row sum
    float p[16];
    float rs = 0.0f;
#pragma unroll
    for (int r = 0; r < 16; r++) {
      p[r] = exp2f(sT[r] - m_run);
      rs += p[r];
    }
    rs += __shfl_xor(rs, 32);
    l_run += rs;

    // pack P -> bf16 pairs; redistribute across hi with shfl_xor(32)
    u32 c[8];
#pragma unroll
    for (int i = 0; i < 8; i++) c[i] = cvtpk(p[2 * i], p[2 * i + 1]);
    u32 x[8];
#pragma unroll
    for (int i = 0; i < 8; i++) x[i] = (u32)__shfl_xor((int)c[i], 32);
    u32x4 w0, w1;
    w0.x = hi ? x[2] : c[0];
    w0.y = hi ? x[3] : c[1];
    w0.z = hi ? c[2] : x[0];
    w0.w = hi ? c[3] : x[1];
    w1.x = hi ? x[6] : c[4];
    w1.y = hi ? x[7] : c[5];
    w1.z = hi ? c[6] : x[4];
    w1.w = hi ? c[7] : x[5];
    bf16x8 pa0 = __builtin_bit_cast(bf16x8, w0);
    bf16x8 pa1 = __builtin_bit_cast(bf16x8, w1);

    // O += P V
    acc[0] = mfma32(pa0, vf[0][0], acc[0]);
    acc[1] = mfma32(pa0, vf[1][0], acc[1]);
    acc[0] = mfma32(pa1, vf[0][1], acc[0]);
    acc[1] = mfma32(pa1, vf[1][1], acc[1]);

    // rotate K prefetch
#pragma unroll
    for (int kk = 0; kk < 4; kk++) kf[kk] = kn[kk];
  }

  // Merge the 4 KV-chunk partials via LDS
  __syncthreads();  // corrL dead; alias smem as accL/mlL
  float* accL = (float*)smem;           // [z][q][65] padded
  float* mlL = (float*)(smem + 33280);  // [z][q][2]
#pragma unroll
  for (int ht = 0; ht < 2; ht++)
#pragma unroll
    for (int r = 0; r < 16; r++) {
      int q = (r & 3) + 8 * (r >> 2) + 4 * hi;
      accL[(w * 32 + q) * 65 + ht * 32 + l31] = acc[ht][r];
    }
  if (hi == 0) {
    mlL[(w * 32 + l31) * 2 + 0] = m_run;
    mlL[(w * 32 + l31) * 2 + 1] = l_run;
  }
  __syncthreads();

#pragma unroll
  for (int i = 0; i < 8; i++) {
    int idx = tid + i * 256;  // 0..2047
    int row = idx >> 6, h = idx & 63;
    float m[4], l[4];
#pragma unroll
    for (int z = 0; z < 4; z++) {
      m[z] = mlL[(z * 32 + row) * 2 + 0];
      l[z] = mlL[(z * 32 + row) * 2 + 1];
    }
    float M = fmaxf(fmaxf(m[0], m[1]), fmaxf(m[2], m[3]));
    float den = 0.0f, o = 0.0f;
#pragma unroll
    for (int z = 0; z < 4; z++) {
      float e = exp2f(m[z] - M);
      den += e * l[z];
      o += e * accL[(z * 32 + row) * 65 + h];
    }
    out[((size_t)b * NS + q0t * 32 + row) * NH + h] = o / den;
  }
}

extern "C" void kernel_launch(void* const* d_in, const int* in_sizes, int n_in,
                              void* d_out, int out_size, void* d_ws,
                              size_t ws_size, hipStream_t stream) {
  const float* inp = (const float*)d_in[0];
  const int* mask = (const int*)d_in[1];
  const float* Wq = (const float*)d_in[2];
  const float* bq = (const float*)d_in[3];
  const float* Wk = (const float*)d_in[4];
  const float* bk = (const float*)d_in[5];
  const float* Wv = (const float*)d_in[6];
  const float* bv = (const float*)d_in[7];
  float* out = (float*)d_out;

  char* ws = (char*)d_ws;
  u16* wsW = (u16*)ws;                              // 288 KB
  u16* wsQf = (u16*)(ws + (1u << 20));              // 4 MB
  u16* wsKf = (u16*)(ws + (1u << 20) + (4u << 20)); // 4 MB
  u16* wsVf = (u16*)(ws + (1u << 20) + (8u << 20)); // 4 MB
  float* wsBias = (float*)(ws + (13u << 20));       // 128 KB

  prep_weights<<<dim3(72), dim3(256), 0, stream>>>(Wq, Wk, Wv, wsW);
  prep_bias<<<dim3(NB * NS / 256), dim3(256), 0, stream>>>(mask, wsBias);
  qkv_proj<<<dim3((NB * NS) / 32), dim3(256), 0, stream>>>(inp, wsW, bq, bk,
                                                           bv, wsQf, wsKf, wsVf);
  attn<<<dim3(NB * NS / 32), dim3(256), 0, stream>>>(wsQf, wsKf, wsVf, wsBias,
                                                     out);
}